// Round 11
// baseline (1236.387 us; speedup 1.0000x reference)
//
#include <hip/hip_runtime.h>
#include <hip/hip_bf16.h>

using bf16 = __hip_bfloat16;

#define N_HOSTN 20000
#define N_FLOWN 200000
#define E_HFN   400000
#define E_RELN  800000
#define GG      64
#define HH      128
#define FIN     97
#define NCN     10

// CSR region block counts (256 threads/block)
#define NB_REL_E 3125   // 800000/256
#define NB_HF_E  1563   // ceil(400000/256)
#define NB_REL_N 782    // ceil(200000/256)
#define NB_F2H_N 79     // ceil(20000/256)
// class-partitioned placement: 2048-edge chunks x 8 classes
#define NCH_REL 391     // ceil(800000/2048)
#define NCH_HF  196     // ceil(400000/2048)
#define PLC_REL (NCH_REL*8)            // 3128
#define PLC_H2F (PLC_REL + NCH_HF*8)   // 4696
#define PLC_ALL (PLC_H2F + NCH_HF*8)   // 6264

static inline int cdiv(long long a, long long b){ return (int)((a + b - 1) / b); }

typedef unsigned uint4n __attribute__((ext_vector_type(4)));   // native vec for nt builtins

__device__ __forceinline__ float bf2f(unsigned short u){
    return __uint_as_float(((unsigned)u) << 16);
}
__device__ __forceinline__ unsigned short f2bf(float f){
    unsigned u = __float_as_uint(f);
    unsigned r = u + 0x7FFFu + ((u >> 16) & 1u);   // RNE
    return (unsigned short)(r >> 16);
}
__device__ __forceinline__ float loadf(const void* p, size_t i, int isbf){
    return isbf ? bf2f(((const unsigned short*)p)[i]) : ((const float*)p)[i];
}
// nontemporal (no-allocate) variants for single-use streams
__device__ __forceinline__ float loadf_nt(const void* p, size_t i, int isbf){
    if (isbf) return bf2f(__builtin_nontemporal_load((const unsigned short*)p + i));
    return __builtin_nontemporal_load((const float*)p + i);
}
__device__ __forceinline__ ushort2 ntload_us2(const unsigned short* p){
    unsigned v = __builtin_nontemporal_load((const unsigned*)p);
    ushort2 r; r.x = (unsigned short)(v & 0xFFFFu); r.y = (unsigned short)(v >> 16);
    return r;
}

// ---------------- dtype detection ----------------
__global__ void k_detect(const unsigned short* x, int* flag){
    __shared__ int bad;
    if (threadIdx.x == 0) bad = 0;
    __syncthreads();
    int b = 0;
    for (int i = threadIdx.x; i < 4096; i += 256) {
        unsigned e = (x[i] >> 7) & 0xFFu;
        if (e >= 0x90u) b++;
    }
    if (b) atomicAdd(&bad, b);
    __syncthreads();
    if (threadIdx.x == 0) *flag = (bad == 0) ? 1 : 0;   // 1 = bf16, 0 = f32
}

// ---------------- misc ----------------
__global__ void k_zero(float* p, size_t n){
    size_t i = (size_t)blockIdx.x * 256 + threadIdx.x;
    if (i < n) p[i] = 0.f;
}
__global__ void k_flag_us(unsigned short* out, int n, unsigned short val){
    int i = blockIdx.x * 256 + threadIdx.x;
    if (i < n) out[i] = val;
}
__global__ void k_gather_embed(const int* ids, const void* emb, float* out, const int* flagp){
    int i = blockIdx.x * 256 + threadIdx.x;
    if (i >= N_HOSTN * HH) return;
    int isbf = *flagp;
    int node = i >> 7, f = i & 127;
    out[i] = loadf(emb, (size_t)ids[node] * HH + f, isbf);
}
// flow_x [N,97] (flag dtype) -> bf16 padded [N,128]  (nt read: single use)
__global__ void k_pad_cast(const void* x, unsigned short* o, const int* flagp){
    size_t i = (size_t)blockIdx.x * 256 + threadIdx.x;
    if (i >= (size_t)N_FLOWN * 128) return;
    int isbf = *flagp;
    int row = (int)(i >> 7), c = (int)i & 127;
    o[i] = (c < FIN) ? f2bf(loadf_nt(x, (size_t)row * FIN + c, isbf)) : (unsigned short)0;
}

// ---------------- one-shot weight prep (833 blocks, region dispatch) ----------------
__global__ __launch_bounds__(256) void k_wprep_all(
    const void* Wr0_h2f, const void* br0_h2f, const void* Wo0_h2f,
    const void* Wr0_f2h, const void* br0_f2h, const void* Wo0_f2h,
    const void* Wr0_rel, const void* br0_rel, const void* Wo0_rel,
    const void* Wr_all, const void* br_all, const void* Wo_all,
    unsigned short* WBT0, unsigned short* WBT1, unsigned short* WBT2,
    float* w_h2f0, float* w_h2f1, float* w_h2f2,
    float* w_f2h0, float* w_f2h1, float* w_of2h0, float* w_of2h1,
    float* b_comb0, float* b_comb1, float* b_comb2, float* b_f2h0, float* b_f2h1,
    const int* flagp)
{
    const int bb = blockIdx.x, t = threadIdx.x;
    const int isbf = *flagp;
    if (bb < 384) {
        int layer = bb >> 7;
        int i = ((bb & 127) << 8) + t;   // 0..32767
        int nn = i >> 7, k = i & 127;
        float v = 0.f;
        if (layer == 0) {
            if (k < FIN) {
                if (nn < 128) v = loadf(Wo0_h2f, (size_t)k*128+nn, isbf) + loadf(Wo0_rel, (size_t)k*128+nn, isbf);
                else          v = loadf(Wr0_rel, (size_t)k*128+(nn-128), isbf);
            }
        } else {
            size_t oW = (size_t)((layer - 1) * 3) * 16384;
            if (nn < 128) v = loadf(Wo_all, oW + (size_t)k*128+nn, isbf)
                            + loadf(Wo_all, oW + 2*16384 + (size_t)k*128+nn, isbf);
            else          v = loadf(Wr_all, oW + 2*16384 + (size_t)k*128+(nn-128), isbf);
        }
        unsigned short* W = (layer == 0) ? WBT0 : ((layer == 1) ? WBT1 : WBT2);
        W[(size_t)nn*128 + k] = f2bf(v);
    } else if (bb < 576) {
        int r = bb - 384; int layer = r >> 6; int i = ((r & 63) << 8) + t;
        float v;
        if (layer == 0) v = loadf(Wr0_h2f, (size_t)i, isbf);
        else            v = loadf(Wr_all, (size_t)((layer-1)*3)*16384 + i, isbf);
        ((layer == 0) ? w_h2f0 : ((layer == 1) ? w_h2f1 : w_h2f2))[i] = v;
    } else if (bb < 640) {
        // w_f2h0 padded to [128][128]: rows k>=97 zero
        int i = ((bb - 576) << 8) + t;
        int k = i >> 7;
        w_f2h0[i] = (k < FIN) ? loadf(Wr0_f2h, (size_t)i, isbf) : 0.f;
    } else if (bb < 704) {
        int i = ((bb - 640) << 8) + t;
        w_f2h1[i] = loadf(Wr_all, (size_t)1*16384 + i, isbf);
    } else if (bb < 768) {
        int i = ((bb - 704) << 8) + t;
        w_of2h0[i] = loadf(Wo0_f2h, (size_t)i, isbf);
    } else if (bb < 832) {
        int i = ((bb - 768) << 8) + t;
        w_of2h1[i] = loadf(Wo_all, (size_t)1*16384 + i, isbf);
    } else {
        if (t < 128) {
            b_comb0[t] = loadf(br0_h2f, t, isbf) + loadf(br0_rel, t, isbf);
            b_comb1[t] = loadf(br_all, 0*128 + t, isbf) + loadf(br_all, 2*128 + t, isbf);
            b_comb2[t] = loadf(br_all, 3*128 + t, isbf) + loadf(br_all, 5*128 + t, isbf);
            b_f2h0[t]  = loadf(br0_f2h, t, isbf);
            b_f2h1[t]  = loadf(br_all, 1*128 + t, isbf);
        }
    }
}

// ---------------- CSR build (3-region batched) ----------------
__global__ void k_zero3(int* c0, int* c1, int* c2){
    int bb = blockIdx.x, t = threadIdx.x;
    int* c; int n; int base;
    if (bb < NB_REL_N)              { c = c0; n = N_FLOWN; base = bb; }
    else if (bb < 2*NB_REL_N)       { c = c1; n = N_FLOWN; base = bb - NB_REL_N; }
    else                            { c = c2; n = N_HOSTN; base = bb - 2*NB_REL_N; }
    int i = base * 256 + t;
    if (i < n) c[i] = 0;
}
__global__ void k_hist3(const int* d0, const int* d1, const int* d2,
                        int* c0, int* c1, int* c2){
    int bb = blockIdx.x, t = threadIdx.x;
    const int* dst; int* cnt; int E; int base;
    if (bb < NB_REL_E)                   { dst = d0; cnt = c0; E = E_RELN; base = bb; }
    else if (bb < NB_REL_E + NB_HF_E)    { dst = d1; cnt = c1; E = E_HFN;  base = bb - NB_REL_E; }
    else                                 { dst = d2; cnt = c2; E = E_HFN;  base = bb - NB_REL_E - NB_HF_E; }
    int e = base * 256 + t;
    if (e < E) atomicAdd(&cnt[dst[e]], 1);
}
__global__ __launch_bounds__(256) void k_scan1_3(
    const int* c0, int* rp0, int* bs0,
    const int* c1, int* rp1, int* bs1,
    const int* c2, int* rp2, int* bs2)
{
    __shared__ int s[256];
    int bb = blockIdx.x, t = threadIdx.x;
    const int* cnt; int* rp; int* bsum; int n; int base;
    if (bb < NB_REL_N)            { cnt = c0; rp = rp0; bsum = bs0; n = N_FLOWN; base = bb; }
    else if (bb < 2*NB_REL_N)     { cnt = c1; rp = rp1; bsum = bs1; n = N_FLOWN; base = bb - NB_REL_N; }
    else                          { cnt = c2; rp = rp2; bsum = bs2; n = N_HOSTN; base = bb - 2*NB_REL_N; }
    int i = base * 256 + t;
    int v = (i < n) ? cnt[i] : 0;
    s[t] = v; __syncthreads();
    for (int off = 1; off < 256; off <<= 1) {
        int x = (t >= off) ? s[t - off] : 0;
        __syncthreads();
        s[t] += x;
        __syncthreads();
    }
    if (i < n) rp[i] = s[t] - v;
    if (t == 255) bsum[base] = s[255];
}
__global__ __launch_bounds__(256) void k_scan2_3(int* bs0, int* bs1, int* bs2){
    __shared__ int s[256];
    __shared__ int carry;
    int t = threadIdx.x;
    int* bsum; int nb;
    if (blockIdx.x == 0)      { bsum = bs0; nb = NB_REL_N; }
    else if (blockIdx.x == 1) { bsum = bs1; nb = NB_REL_N; }
    else                      { bsum = bs2; nb = NB_F2H_N; }
    if (t == 0) carry = 0;
    __syncthreads();
    for (int base = 0; base < nb; base += 256) {
        int i = base + t;
        int v = (i < nb) ? bsum[i] : 0;
        s[t] = v; __syncthreads();
        for (int off = 1; off < 256; off <<= 1) {
            int x = (t >= off) ? s[t - off] : 0;
            __syncthreads();
            s[t] += x;
            __syncthreads();
        }
        int excl = s[t] - v + carry;
        if (i < nb) bsum[i] = excl;
        __syncthreads();
        if (t == 255) carry += s[255];
        __syncthreads();
    }
}
__global__ void k_scan3_3(int* rp0, const int* bs0, int* w0,
                          int* rp1, const int* bs1, int* w1,
                          int* rp2, const int* bs2, int* w2)
{
    int bb = blockIdx.x, t = threadIdx.x;
    int* rp; const int* bsum; int* wr; int n, E, base;
    if (bb < NB_REL_N)        { rp = rp0; bsum = bs0; wr = w0; n = N_FLOWN; E = E_RELN; base = bb; }
    else if (bb < 2*NB_REL_N) { rp = rp1; bsum = bs1; wr = w1; n = N_FLOWN; E = E_HFN;  base = bb - NB_REL_N; }
    else                      { rp = rp2; bsum = bs2; wr = w2; n = N_HOSTN; E = E_HFN;  base = bb - 2*NB_REL_N; }
    int i = base * 256 + t;
    if (i < n) { int v = rp[i] + bsum[base]; rp[i] = v; wr[i] = v; }
    if (i == 0) rp[n] = E;
}
// class-partitioned placement: class = blockIdx%8 (round-robins onto XCDs);
// each ei/wr line belongs to one dst class -> single-XCD writes (heuristic).
__global__ __launch_bounds__(256) void k_place3c(
    const int* s0, const int* d0, int* w0, int* e0,
    const int* s1, const int* d1, int* w1, int* e1,
    const int* s2, const int* d2, int* w2, int* e2)
{
    const int bb = blockIdx.x;
    const int *src, *dst; int *wr, *ei; int E, divc, rb;
    if (bb < PLC_REL)      { src=s0; dst=d0; wr=w0; ei=e0; E=E_RELN; divc=25000; rb=bb; }
    else if (bb < PLC_H2F) { src=s1; dst=d1; wr=w1; ei=e1; E=E_HFN;  divc=25000; rb=bb-PLC_REL; }
    else                   { src=s2; dst=d2; wr=w2; ei=e2; E=E_HFN;  divc=2500;  rb=bb-PLC_H2F; }
    const int cls  = rb & 7;
    const int base = (rb >> 3) * 2048;
    const int t = threadIdx.x;
    #pragma unroll
    for (int i = 0; i < 8; ++i) {
        const int e = base + t + i * 256;
        if (e < E) {
            const int d = dst[e];
            if (d / divc == cls) {
                const int pos = atomicAdd(&wr[d], 1);
                ei[pos] = src[e];
            }
        }
    }
}

// ---------------- host-sized VALU GEMM: Y[M,128] (+)= X[M,K]@W[K,128]+b ---------
__global__ __launch_bounds__(256) void k_gemm128(
    const void* X, int xmode, const float* W, const float* bias,
    void* Y, int ybf, int M, int K, int accum, int dorelu, const int* flagp)
{
    const int isbf = (xmode == 2) ? *flagp : xmode;
    const int tid  = threadIdx.x;
    const int row0 = blockIdx.x * 16;
    __shared__ float sX[16][130];
    const int total = 16 * K;
    for (int i = tid; i < total; i += 256) {
        int r = i / K, c = i - r * K;
        int gr = row0 + r;
        sX[r][c] = (gr < M) ? loadf(X, (size_t)gr * K + c, isbf) : 0.f;
    }
    __syncthreads();

    const int c4 = (tid & 31) * 4;
    const int rb = tid >> 5;
    float a0x=0,a0y=0,a0z=0,a0w=0, a1x=0,a1y=0,a1z=0,a1w=0;
    #pragma unroll 4
    for (int k = 0; k < K; ++k) {
        const float4 w = *(const float4*)(W + (size_t)k * 128 + c4);
        const float x0 = sX[rb][k];
        const float x1 = sX[rb + 8][k];
        a0x = fmaf(x0, w.x, a0x); a0y = fmaf(x0, w.y, a0y);
        a0z = fmaf(x0, w.z, a0z); a0w = fmaf(x0, w.w, a0w);
        a1x = fmaf(x1, w.x, a1x); a1y = fmaf(x1, w.y, a1y);
        a1z = fmaf(x1, w.z, a1z); a1w = fmaf(x1, w.w, a1w);
    }
    float bx=0, by=0, bz=0, bw=0;
    if (bias) { const float4 b = *(const float4*)(bias + c4); bx=b.x; by=b.y; bz=b.z; bw=b.w; }

    #pragma unroll
    for (int h = 0; h < 2; ++h) {
        const int rr = row0 + rb + (h ? 8 : 0);
        if (rr >= M) continue;
        float v0 = (h?a1x:a0x)+bx, v1 = (h?a1y:a0y)+by;
        float v2 = (h?a1z:a0z)+bz, v3 = (h?a1w:a0w)+bw;
        if (ybf) {
            unsigned short* p = (unsigned short*)Y + (size_t)rr * 128 + c4;
            ushort4 o; o.x=f2bf(v0); o.y=f2bf(v1); o.z=f2bf(v2); o.w=f2bf(v3);
            *(ushort4*)p = o;
        } else {
            float* p = (float*)Y + (size_t)rr * 128 + c4;
            if (accum) { v0+=p[0]; v1+=p[1]; v2+=p[2]; v3+=p[3]; }
            if (dorelu) { v0=fmaxf(v0,0.f); v1=fmaxf(v1,0.f); v2=fmaxf(v2,0.f); v3=fmaxf(v3,0.f); }
            float4 o; o.x=v0; o.y=v1; o.z=v2; o.w=v3;
            *(float4*)p = o;
        }
    }
}

// ---------------- fused dual-input host GEMM: Y = relu(X1@W1 + X2@W2 + b) ------
__global__ __launch_bounds__(256) void k_gemm2in(
    const float* __restrict__ X1, const float* __restrict__ X2,
    const float* __restrict__ W1, const float* __restrict__ W2,
    const float* __restrict__ bias, float* __restrict__ Y, int M)
{
    const int tid  = threadIdx.x;
    const int row0 = blockIdx.x * 16;
    __shared__ float sX1[16][130];
    __shared__ float sX2[16][130];
    for (int i = tid; i < 16 * 128; i += 256) {
        int r = i >> 7, c = i & 127;
        int gr = row0 + r;
        sX1[r][c] = (gr < M) ? X1[(size_t)gr * 128 + c] : 0.f;
        sX2[r][c] = (gr < M) ? X2[(size_t)gr * 128 + c] : 0.f;
    }
    __syncthreads();

    const int c4 = (tid & 31) * 4;
    const int rb = tid >> 5;
    float a0x=0,a0y=0,a0z=0,a0w=0, a1x=0,a1y=0,a1z=0,a1w=0;
    #pragma unroll 4
    for (int k = 0; k < 128; ++k) {
        const float4 w = *(const float4*)(W1 + (size_t)k * 128 + c4);
        const float x0 = sX1[rb][k];
        const float x1 = sX1[rb + 8][k];
        a0x = fmaf(x0, w.x, a0x); a0y = fmaf(x0, w.y, a0y);
        a0z = fmaf(x0, w.z, a0z); a0w = fmaf(x0, w.w, a0w);
        a1x = fmaf(x1, w.x, a1x); a1y = fmaf(x1, w.y, a1y);
        a1z = fmaf(x1, w.z, a1z); a1w = fmaf(x1, w.w, a1w);
    }
    #pragma unroll 4
    for (int k = 0; k < 128; ++k) {
        const float4 w = *(const float4*)(W2 + (size_t)k * 128 + c4);
        const float x0 = sX2[rb][k];
        const float x1 = sX2[rb + 8][k];
        a0x = fmaf(x0, w.x, a0x); a0y = fmaf(x0, w.y, a0y);
        a0z = fmaf(x0, w.z, a0z); a0w = fmaf(x0, w.w, a0w);
        a1x = fmaf(x1, w.x, a1x); a1y = fmaf(x1, w.y, a1y);
        a1z = fmaf(x1, w.z, a1z); a1w = fmaf(x1, w.w, a1w);
    }
    const float4 b = *(const float4*)(bias + c4);
    #pragma unroll
    for (int h = 0; h < 2; ++h) {
        const int rr = row0 + rb + (h ? 8 : 0);
        if (rr >= M) continue;
        float4 o;
        o.x = fmaxf((h?a1x:a0x) + b.x, 0.f);
        o.y = fmaxf((h?a1y:a0y) + b.y, 0.f);
        o.z = fmaxf((h?a1z:a0z) + b.z, 0.f);
        o.w = fmaxf((h?a1w:a0w) + b.w, 0.f);
        *(float4*)(Y + (size_t)rr * 128 + c4) = o;
    }
}

// ---------------- MFMA dual flow GEMM: both outputs bf16, no bias ----------------
typedef __attribute__((ext_vector_type(8))) short bfrag;
typedef __attribute__((ext_vector_type(4))) float f32x4;

__global__ __launch_bounds__(256) void k_gemm_mfma(
    const unsigned short* __restrict__ Abf, const unsigned short* __restrict__ WBT,
    unsigned short* __restrict__ Y1, unsigned short* __restrict__ Y2, int M)
{
    const int tid  = threadIdx.x;
    const int wave = tid >> 6;
    const int lane = tid & 63;
    const int quad = lane >> 4;
    const int l16  = lane & 15;
    const int m0   = blockIdx.x * 32;

    __shared__ unsigned short sA[32 * 128];   // 8 KB, XOR-swizzled 16B units

    {   // nt read: Abf row-block is consumed exactly once here
        const uint4n* gsrc = (const uint4n*)(Abf + (size_t)m0 * 128);
        uint4n* sdst = (uint4n*)sA;
        #pragma unroll
        for (int p = 0; p < 2; ++p) {
            int g = tid + p * 256;
            int row = g >> 4, u = g & 15;
            sdst[row * 16 + (u ^ (row & 15))] = __builtin_nontemporal_load(gsrc + g);
        }
    }
    __syncthreads();

    f32x4 acc[2][4] = {};
    const int nbase = wave * 64;

    #pragma unroll
    for (int c = 0; c < 4; ++c) {
        const int un = (c * 4 + quad) ^ l16;
        bfrag a0 = *(const bfrag*)(sA + ((size_t)(l16)      * 128 + un * 8));
        bfrag a1 = *(const bfrag*)(sA + ((size_t)(16 + l16) * 128 + un * 8));
        #pragma unroll
        for (int j = 0; j < 4; ++j) {
            const bfrag b = *(const bfrag*)(WBT + (size_t)(nbase + j * 16 + l16) * 128
                                                 + c * 32 + quad * 8);
            acc[0][j] = __builtin_amdgcn_mfma_f32_16x16x32_bf16(a0, b, acc[0][j], 0, 0, 0);
            acc[1][j] = __builtin_amdgcn_mfma_f32_16x16x32_bf16(a1, b, acc[1][j], 0, 0, 0);
        }
    }

    if (nbase < 128) {
        // Y1 = Froot: read exactly once (streaming) by agg_flow -> nt store
        #pragma unroll
        for (int j = 0; j < 4; ++j) {
            const int col = nbase + j * 16 + l16;
            #pragma unroll
            for (int i = 0; i < 2; ++i)
                #pragma unroll
                for (int r = 0; r < 4; ++r) {
                    const int row = m0 + i * 16 + quad * 4 + r;
                    __builtin_nontemporal_store(f2bf(acc[i][j][r]),
                                                Y1 + (size_t)row * 128 + col);
                }
        }
    } else {
        // Y2 = F2bf: random-gather target -> keep cacheable
        #pragma unroll
        for (int j = 0; j < 4; ++j) {
            const int col = (nbase - 128) + j * 16 + l16;
            #pragma unroll
            for (int i = 0; i < 2; ++i)
                #pragma unroll
                for (int r = 0; r < 4; ++r) {
                    const int row = m0 + i * 16 + quad * 4 + r;
                    Y2[(size_t)row * 128 + col] = f2bf(acc[i][j][r]);
                }
        }
    }
}

// ---------------- CSR gather-aggregation (all-bf16, 4 dst/block, chunk-4 MLP) ----
// Xout[d] = relu?( root[d] + bias + sum_rel Zrel[s] + sum_h2f Zh2f[s] )
__global__ __launch_bounds__(256) void k_agg_flow(
    const unsigned short* __restrict__ Zrel, const unsigned short* __restrict__ Zh2f,
    const int* __restrict__ rp_rel, const int* __restrict__ ei_rel,
    const int* __restrict__ rp_h2f, const int* __restrict__ ei_h2f,
    const unsigned short* __restrict__ root, const float* __restrict__ bias,
    unsigned short* __restrict__ Xout, int do_relu)
{
    const int wave = threadIdx.x >> 6;
    const int lane = threadIdx.x & 63;
    const int d = blockIdx.x * 4 + wave;
    const int f2 = lane * 2;

    const ushort2 rv = ntload_us2(root + (size_t)d * 128 + f2);   // nt: root read once
    const float2 bv = *(const float2*)(bias + f2);
    float a0 = bf2f(rv.x) + bv.x;
    float a1 = bf2f(rv.y) + bv.y;

    {   // rel edges: chunks of 4 -> 4 gathers in flight
        const int b0 = rp_rel[d], b1 = rp_rel[d + 1];
        int e = b0;
        for (; e + 4 <= b1; e += 4) {
            const int s0 = ei_rel[e];
            const int s1 = ei_rel[e + 1];
            const int s2 = ei_rel[e + 2];
            const int s3 = ei_rel[e + 3];
            const ushort2 z0 = *(const ushort2*)(Zrel + (size_t)s0 * 128 + f2);
            const ushort2 z1 = *(const ushort2*)(Zrel + (size_t)s1 * 128 + f2);
            const ushort2 z2 = *(const ushort2*)(Zrel + (size_t)s2 * 128 + f2);
            const ushort2 z3 = *(const ushort2*)(Zrel + (size_t)s3 * 128 + f2);
            a0 += (bf2f(z0.x) + bf2f(z1.x)) + (bf2f(z2.x) + bf2f(z3.x));
            a1 += (bf2f(z0.y) + bf2f(z1.y)) + (bf2f(z2.y) + bf2f(z3.y));
        }
        if (e + 2 <= b1) {
            const int s0 = ei_rel[e];
            const int s1 = ei_rel[e + 1];
            const ushort2 z0 = *(const ushort2*)(Zrel + (size_t)s0 * 128 + f2);
            const ushort2 z1 = *(const ushort2*)(Zrel + (size_t)s1 * 128 + f2);
            a0 += bf2f(z0.x) + bf2f(z1.x);
            a1 += bf2f(z0.y) + bf2f(z1.y);
            e += 2;
        }
        if (e < b1) {
            const int s = ei_rel[e];
            const ushort2 z = *(const ushort2*)(Zrel + (size_t)s * 128 + f2);
            a0 += bf2f(z.x); a1 += bf2f(z.y);
        }
    }
    {   // h2f edges: chunks of 4 + tail
        const int b0 = rp_h2f[d], b1 = rp_h2f[d + 1];
        int e = b0;
        for (; e + 4 <= b1; e += 4) {
            const int s0 = ei_h2f[e];
            const int s1 = ei_h2f[e + 1];
            const int s2 = ei_h2f[e + 2];
            const int s3 = ei_h2f[e + 3];
            const ushort2 z0 = *(const ushort2*)(Zh2f + (size_t)s0 * 128 + f2);
            const ushort2 z1 = *(const ushort2*)(Zh2f + (size_t)s1 * 128 + f2);
            const ushort2 z2 = *(const ushort2*)(Zh2f + (size_t)s2 * 128 + f2);
            const ushort2 z3 = *(const ushort2*)(Zh2f + (size_t)s3 * 128 + f2);
            a0 += (bf2f(z0.x) + bf2f(z1.x)) + (bf2f(z2.x) + bf2f(z3.x));
            a1 += (bf2f(z0.y) + bf2f(z1.y)) + (bf2f(z2.y) + bf2f(z3.y));
        }
        if (e + 2 <= b1) {
            const int s0 = ei_h2f[e];
            const int s1 = ei_h2f[e + 1];
            const ushort2 z0 = *(const ushort2*)(Zh2f + (size_t)s0 * 128 + f2);
            const ushort2 z1 = *(const ushort2*)(Zh2f + (size_t)s1 * 128 + f2);
            a0 += bf2f(z0.x) + bf2f(z1.x);
            a1 += bf2f(z0.y) + bf2f(z1.y);
            e += 2;
        }
        if (e < b1) {
            const int s = ei_h2f[e];
            const ushort2 z = *(const ushort2*)(Zh2f + (size_t)s * 128 + f2);
            a0 += bf2f(z.x); a1 += bf2f(z.y);
        }
    }
    if (do_relu) { a0 = fmaxf(a0, 0.f); a1 = fmaxf(a1, 0.f); }
    ushort2 o; o.x = f2bf(a0); o.y = f2bf(a1);
    *(ushort2*)(Xout + (size_t)d * 128 + f2) = o;
}

// host dst: out[d][0:128] = sum f2h Zbf[src][0:128]  (window-8 MLP)
__global__ __launch_bounds__(128) void k_agg_host(
    const unsigned short* __restrict__ Z, const int* __restrict__ rp,
    const int* __restrict__ ei, float* __restrict__ out)
{
    const int d = blockIdx.x, t = threadIdx.x;
    const int b0 = rp[d];
    const int n = rp[d + 1] - b0;
    float a = 0.f;
    for (int base = 0; base < n; base += 8) {
        const int cnt = min(8, n - base);
        unsigned short z[8];
        #pragma unroll
        for (int q = 0; q < 8; ++q)
            if (q < cnt) z[q] = Z[(size_t)ei[b0 + base + q] * 128 + t];
        #pragma unroll
        for (int q = 0; q < 8; ++q)
            if (q < cnt) a += bf2f(z[q]);
    }
    out[(size_t)d * 128 + t] = a;
}

// ---------------- pooling over sorted batch (bf16 input, nt read) ----------------
#define PCHUNK 128
__global__ __launch_bounds__(128) void k_pool2(const unsigned short* xf, const int* batch,
                                               unsigned* bits){
    const int t = threadIdx.x;
    const int i0 = blockIdx.x * PCHUNK;
    const int iend = min(i0 + PCHUNK, N_FLOWN);
    if (i0 >= N_FLOWN) return;
    float cur = -3.4e38f;
    int curg = batch[i0];
    for (int i = i0; i < iend; ++i) {
        int g = batch[i];
        if (g != curg) {
            unsigned u = __float_as_uint(cur);
            unsigned ord = (u & 0x80000000u) ? ~u : (u | 0x80000000u);
            atomicMax(&bits[(size_t)curg * 128 + t], ord);
            cur = -3.4e38f; curg = g;
        }
        cur = fmaxf(cur, bf2f(__builtin_nontemporal_load(xf + (size_t)i * 128 + t)));
    }
    unsigned u = __float_as_uint(cur);
    unsigned ord = (u & 0x80000000u) ? ~u : (u | 0x80000000u);
    atomicMax(&bits[(size_t)curg * 128 + t], ord);
}

// ---------------- classifier ----------------
__global__ __launch_bounds__(128) void k_classifier(
    const unsigned* bits,
    const void* Wc1, const void* bc1, const void* Wc2, const void* bc2,
    const void* Wc3, const void* bc3, void* out, const int* flagp)
{
    const int g = blockIdx.x, t = threadIdx.x;
    const int isbf = *flagp;
    __shared__ float sp[128], sh1[64], sh2[128];
    {
        unsigned ord = bits[(size_t)g * HH + t];
        unsigned u = (ord & 0x80000000u) ? (ord & 0x7FFFFFFFu) : ~ord;
        sp[t] = __uint_as_float(u);
    }
    __syncthreads();
    if (t < 64) {
        float a = loadf(bc1, t, isbf);
        #pragma unroll 4
        for (int k = 0; k < 128; ++k) a = fmaf(sp[k], loadf(Wc1, k * 64 + t, isbf), a);
        sh1[t] = fmaxf(a, 0.f);
    }
    __syncthreads();
    {
        float a = loadf(bc2, t, isbf);
        #pragma unroll 4
        for (int k = 0; k < 64; ++k) a = fmaf(sh1[k], loadf(Wc2, k * 128 + t, isbf), a);
        sh2[t] = fmaxf(a, 0.f);
    }
    __syncthreads();
    if (t < NCN) {
        float a = loadf(bc3, t, isbf);
        #pragma unroll 4
        for (int k = 0; k < 128; ++k) a = fmaf(sh2[k], loadf(Wc3, k * NCN + t, isbf), a);
        if (isbf) ((unsigned short*)out)[(size_t)g * NCN + t] = f2bf(a);
        else      ((float*)out)[(size_t)g * NCN + t] = a;
    }
}

extern "C" void kernel_launch(void* const* d_in, const int* in_sizes, int n_in,
                              void* d_out, int out_size, void* d_ws, size_t ws_size,
                              hipStream_t stream)
{
    const int*  host_ids   = (const int*) d_in[0];
    const void* flow_x     = d_in[1];
    const int*  h2f_src    = (const int*) d_in[2];
    const int*  h2f_dst    = (const int*) d_in[3];
    const int*  f2h_src    = (const int*) d_in[4];
    const int*  f2h_dst    = (const int*) d_in[5];
    const int*  rel_src    = (const int*) d_in[6];
    const int*  rel_dst    = (const int*) d_in[7];
    const int*  flow_batch = (const int*) d_in[8];
    const void* host_embed = d_in[9];
    const void* Wr0_h2f = d_in[10]; const void* br0_h2f = d_in[11]; const void* Wo0_h2f = d_in[12];
    const void* Wr0_f2h = d_in[13]; const void* br0_f2h = d_in[14]; const void* Wo0_f2h = d_in[15];
    const void* Wr0_rel = d_in[16]; const void* br0_rel = d_in[17]; const void* Wo0_rel = d_in[18];
    const void* Wr_all  = d_in[19];
    const void* br_all  = d_in[20];
    const void* Wo_all  = d_in[21];
    const void* Wc1 = d_in[22]; const void* bc1 = d_in[23];
    const void* Wc2 = d_in[24]; const void* bc2 = d_in[25];
    const void* Wc3 = d_in[26]; const void* bc3 = d_in[27];

    // -------- workspace (~200 MB) --------
    size_t off = 0;
    auto alloc = [&](size_t bytes) -> char* {
        char* p = (char*)d_ws + off;
        off += (bytes + 255) & ~(size_t)255;
        return p;
    };
    unsigned short* F1bf  = (unsigned short*)alloc((size_t)N_FLOWN * HH * 2);  // state
    unsigned short* Froot = (unsigned short*)alloc((size_t)N_FLOWN * HH * 2);  // root term
    unsigned short* F2bf  = (unsigned short*)alloc((size_t)N_FLOWN * HH * 2);  // z_rel
    float* HA = (float*)alloc((size_t)N_HOSTN * HH * 4);
    float* HB = (float*)alloc((size_t)N_HOSTN * HH * 4);
    unsigned short* HCbf = (unsigned short*)alloc((size_t)N_HOSTN * HH * 2);   // z_h
    float* HD = (float*)alloc((size_t)N_HOSTN * HH * 4);
    unsigned short* WBT0 = (unsigned short*)alloc(256 * 128 * 2);
    unsigned short* WBT1 = (unsigned short*)alloc(256 * 128 * 2);
    unsigned short* WBT2 = (unsigned short*)alloc(256 * 128 * 2);
    float* w_h2f0  = (float*)alloc(128 * 128 * 4);
    float* w_h2f1  = (float*)alloc(128 * 128 * 4);
    float* w_h2f2  = (float*)alloc(128 * 128 * 4);
    float* w_f2h0  = (float*)alloc(128 * 128 * 4);
    float* w_f2h1  = (float*)alloc(128 * 128 * 4);
    float* w_of2h0 = (float*)alloc(128 * 128 * 4);
    float* w_of2h1 = (float*)alloc(128 * 128 * 4);
    float* b_comb0 = (float*)alloc(128 * 4);
    float* b_comb1 = (float*)alloc(128 * 4);
    float* b_comb2 = (float*)alloc(128 * 4);
    float* b_f2h0  = (float*)alloc(128 * 4);
    float* b_f2h1  = (float*)alloc(128 * 4);
    unsigned* poolbits = (unsigned*)alloc(GG * HH * 4);
    int* flagp = (int*)alloc(256);
    int* rp_rel = (int*)alloc((N_FLOWN + 1) * 4);
    int* ei_rel = (int*)alloc((size_t)E_RELN * 4);
    int* rp_h2f = (int*)alloc((N_FLOWN + 1) * 4);
    int* ei_h2f = (int*)alloc((size_t)E_HFN * 4);
    int* rp_f2h = (int*)alloc((N_HOSTN + 1) * 4);
    int* ei_f2h = (int*)alloc((size_t)E_HFN * 4);
    int* wr_rel = (int*)alloc((size_t)N_FLOWN * 4);
    int* wr_h2f = (int*)alloc((size_t)N_FLOWN * 4);
    int* wr_f2h = (int*)alloc((size_t)N_HOSTN * 4);
    int* bs0 = (int*)alloc(1024 * 4);
    int* bs1 = (int*)alloc(1024 * 4);
    int* bs2 = (int*)alloc(256 * 4);

    const int T = 256;
    #define GRID1(n) dim3(cdiv((long long)(n), T)), dim3(T), 0, stream

    if (off > ws_size) {
        k_flag_us<<<GRID1(out_size)>>>((unsigned short*)d_out, out_size, (unsigned short)0x4000);
        return;
    }

    k_detect<<<dim3(1), dim3(256), 0, stream>>>((const unsigned short*)flow_x, flagp);

    // -------- CSR builds (batched, 6 launches) --------
    k_zero3 <<<dim3(2*NB_REL_N + NB_F2H_N), dim3(256), 0, stream>>>(wr_rel, wr_h2f, wr_f2h);
    k_hist3 <<<dim3(NB_REL_E + 2*NB_HF_E), dim3(256), 0, stream>>>(rel_dst, h2f_dst, f2h_dst,
                                                                    wr_rel, wr_h2f, wr_f2h);
    k_scan1_3<<<dim3(2*NB_REL_N + NB_F2H_N), dim3(256), 0, stream>>>(
        wr_rel, rp_rel, bs0, wr_h2f, rp_h2f, bs1, wr_f2h, rp_f2h, bs2);
    k_scan2_3<<<dim3(3), dim3(256), 0, stream>>>(bs0, bs1, bs2);
    k_scan3_3<<<dim3(2*NB_REL_N + NB_F2H_N), dim3(256), 0, stream>>>(
        rp_rel, bs0, wr_rel, rp_h2f, bs1, wr_h2f, rp_f2h, bs2, wr_f2h);
    k_place3c<<<dim3(PLC_ALL), dim3(256), 0, stream>>>(
        rel_src, rel_dst, wr_rel, ei_rel,
        h2f_src, h2f_dst, wr_h2f, ei_h2f,
        f2h_src, f2h_dst, wr_f2h, ei_f2h);

    // -------- weight prep (1 launch) --------
    k_wprep_all<<<dim3(833), dim3(256), 0, stream>>>(
        Wr0_h2f, br0_h2f, Wo0_h2f, Wr0_f2h, br0_f2h, Wo0_f2h, Wr0_rel, br0_rel, Wo0_rel,
        Wr_all, br_all, Wo_all,
        WBT0, WBT1, WBT2, w_h2f0, w_h2f1, w_h2f2,
        w_f2h0, w_f2h1, w_of2h0, w_of2h1,
        b_comb0, b_comb1, b_comb2, b_f2h0, b_f2h1, flagp);

    // ================= layer 0 =================
    k_gather_embed<<<GRID1(N_HOSTN * HH)>>>(host_ids, host_embed, HA, flagp);
    k_pad_cast<<<GRID1((size_t)N_FLOWN * 128)>>>(flow_x, F1bf, flagp);
    // host path: gather bf16 input features (K padded to 128); fused dual GEMM + relu
    k_agg_host<<<dim3(N_HOSTN), dim3(128), 0, stream>>>(F1bf, rp_f2h, ei_f2h, HD);
    k_gemm2in<<<dim3(cdiv(N_HOSTN,16)), dim3(256), 0, stream>>>(HD, HA, w_f2h0, w_of2h0, b_f2h0, HB, N_HOSTN);
    // flow path
    k_gemm128<<<dim3(cdiv(N_HOSTN,16)), dim3(256), 0, stream>>>(HA, 0, w_h2f0, nullptr, HCbf, 1, N_HOSTN, 128, 0, 0, flagp);
    k_gemm_mfma<<<dim3(N_FLOWN/32), dim3(256), 0, stream>>>(F1bf, WBT0, Froot, F2bf, N_FLOWN);
    k_agg_flow<<<dim3(N_FLOWN/4), dim3(256), 0, stream>>>(F2bf, HCbf, rp_rel, ei_rel, rp_h2f, ei_h2f,
                                                          Froot, b_comb0, F1bf, 1);

    // ================= stacked layer 0 =================
    k_agg_host<<<dim3(N_HOSTN), dim3(128), 0, stream>>>(F1bf, rp_f2h, ei_f2h, HD);
    k_gemm128<<<dim3(cdiv(N_HOSTN,16)), dim3(256), 0, stream>>>(HB, 0, w_h2f1, nullptr, HCbf, 1, N_HOSTN, 128, 0, 0, flagp);
    k_gemm_mfma<<<dim3(N_FLOWN/32), dim3(256), 0, stream>>>(F1bf, WBT1, Froot, F2bf, N_FLOWN);
    k_agg_flow<<<dim3(N_FLOWN/4), dim3(256), 0, stream>>>(F2bf, HCbf, rp_rel, ei_rel, rp_h2f, ei_h2f,
                                                          Froot, b_comb1, F1bf, 1);
    k_gemm2in<<<dim3(cdiv(N_HOSTN,16)), dim3(256), 0, stream>>>(HD, HB, w_f2h1, w_of2h1, b_f2h1, HA, N_HOSTN);

    // ================= stacked layer 1 (last; no host update, no relu) =================
    k_gemm128<<<dim3(cdiv(N_HOSTN,16)), dim3(256), 0, stream>>>(HA, 0, w_h2f2, nullptr, HCbf, 1, N_HOSTN, 128, 0, 0, flagp);
    k_gemm_mfma<<<dim3(N_FLOWN/32), dim3(256), 0, stream>>>(F1bf, WBT2, Froot, F2bf, N_FLOWN);
    k_agg_flow<<<dim3(N_FLOWN/4), dim3(256), 0, stream>>>(F2bf, HCbf, rp_rel, ei_rel, rp_h2f, ei_h2f,
                                                          Froot, b_comb2, F1bf, 0);

    // ================= pool + classifier =================
    k_zero<<<GRID1(GG * HH)>>>((float*)poolbits, (size_t)GG * HH);
    k_pool2<<<dim3(cdiv(N_FLOWN, PCHUNK)), dim3(128), 0, stream>>>(F1bf, flow_batch, poolbits);
    k_classifier<<<dim3(GG), dim3(128), 0, stream>>>(poolbits, Wc1, bc1, Wc2, bc2, Wc3, bc3,
                                                     d_out, flagp);
    #undef GRID1
}

// Round 12
// 1195.711 us; speedup vs baseline: 1.0340x; 1.0340x over previous
//
#include <hip/hip_runtime.h>
#include <hip/hip_bf16.h>

using bf16 = __hip_bfloat16;

#define N_HOSTN 20000
#define N_FLOWN 200000
#define E_HFN   400000
#define E_RELN  800000
#define GG      64
#define HH      128
#define FIN     97
#define NCN     10

// CSR region block counts (256 threads/block)
#define NB_REL_E 3125   // 800000/256
#define NB_HF_E  1563   // ceil(400000/256)
#define NB_REL_N 782    // ceil(200000/256)
#define NB_F2H_N 79     // ceil(20000/256)
// class-partitioned placement: 2048-edge chunks x 8 classes
#define NCH_REL 391     // ceil(800000/2048)
#define NCH_HF  196     // ceil(400000/2048)
#define PLC_REL (NCH_REL*8)            // 3128
#define PLC_H2F (PLC_REL + NCH_HF*8)   // 4696
#define PLC_ALL (PLC_H2F + NCH_HF*8)   // 6264

static inline int cdiv(long long a, long long b){ return (int)((a + b - 1) / b); }

__device__ __forceinline__ float bf2f(unsigned short u){
    return __uint_as_float(((unsigned)u) << 16);
}
__device__ __forceinline__ unsigned short f2bf(float f){
    unsigned u = __float_as_uint(f);
    unsigned r = u + 0x7FFFu + ((u >> 16) & 1u);   // RNE
    return (unsigned short)(r >> 16);
}
__device__ __forceinline__ float loadf(const void* p, size_t i, int isbf){
    return isbf ? bf2f(((const unsigned short*)p)[i]) : ((const float*)p)[i];
}

// ---------------- dtype detection ----------------
__global__ void k_detect(const unsigned short* x, int* flag){
    __shared__ int bad;
    if (threadIdx.x == 0) bad = 0;
    __syncthreads();
    int b = 0;
    for (int i = threadIdx.x; i < 4096; i += 256) {
        unsigned e = (x[i] >> 7) & 0xFFu;
        if (e >= 0x90u) b++;
    }
    if (b) atomicAdd(&bad, b);
    __syncthreads();
    if (threadIdx.x == 0) *flag = (bad == 0) ? 1 : 0;   // 1 = bf16, 0 = f32
}

// ---------------- misc ----------------
__global__ void k_zero(float* p, size_t n){
    size_t i = (size_t)blockIdx.x * 256 + threadIdx.x;
    if (i < n) p[i] = 0.f;
}
__global__ void k_flag_us(unsigned short* out, int n, unsigned short val){
    int i = blockIdx.x * 256 + threadIdx.x;
    if (i < n) out[i] = val;
}
__global__ void k_gather_embed(const int* ids, const void* emb, float* out, const int* flagp){
    int i = blockIdx.x * 256 + threadIdx.x;
    if (i >= N_HOSTN * HH) return;
    int isbf = *flagp;
    int node = i >> 7, f = i & 127;
    out[i] = loadf(emb, (size_t)ids[node] * HH + f, isbf);
}
// flow_x [N,97] (flag dtype) -> bf16 padded [N,128]
__global__ void k_pad_cast(const void* x, unsigned short* o, const int* flagp){
    size_t i = (size_t)blockIdx.x * 256 + threadIdx.x;
    if (i >= (size_t)N_FLOWN * 128) return;
    int isbf = *flagp;
    int row = (int)(i >> 7), c = (int)i & 127;
    o[i] = (c < FIN) ? f2bf(loadf(x, (size_t)row * FIN + c, isbf)) : (unsigned short)0;
}

// ---------------- one-shot weight prep (833 blocks, region dispatch) ----------------
__global__ __launch_bounds__(256) void k_wprep_all(
    const void* Wr0_h2f, const void* br0_h2f, const void* Wo0_h2f,
    const void* Wr0_f2h, const void* br0_f2h, const void* Wo0_f2h,
    const void* Wr0_rel, const void* br0_rel, const void* Wo0_rel,
    const void* Wr_all, const void* br_all, const void* Wo_all,
    unsigned short* WBT0, unsigned short* WBT1, unsigned short* WBT2,
    float* w_h2f0, float* w_h2f1, float* w_h2f2,
    float* w_f2h0, float* w_f2h1, float* w_of2h0, float* w_of2h1,
    float* b_comb0, float* b_comb1, float* b_comb2, float* b_f2h0, float* b_f2h1,
    const int* flagp)
{
    const int bb = blockIdx.x, t = threadIdx.x;
    const int isbf = *flagp;
    if (bb < 384) {
        int layer = bb >> 7;
        int i = ((bb & 127) << 8) + t;   // 0..32767
        int nn = i >> 7, k = i & 127;
        float v = 0.f;
        if (layer == 0) {
            if (k < FIN) {
                if (nn < 128) v = loadf(Wo0_h2f, (size_t)k*128+nn, isbf) + loadf(Wo0_rel, (size_t)k*128+nn, isbf);
                else          v = loadf(Wr0_rel, (size_t)k*128+(nn-128), isbf);
            }
        } else {
            size_t oW = (size_t)((layer - 1) * 3) * 16384;
            if (nn < 128) v = loadf(Wo_all, oW + (size_t)k*128+nn, isbf)
                            + loadf(Wo_all, oW + 2*16384 + (size_t)k*128+nn, isbf);
            else          v = loadf(Wr_all, oW + 2*16384 + (size_t)k*128+(nn-128), isbf);
        }
        unsigned short* W = (layer == 0) ? WBT0 : ((layer == 1) ? WBT1 : WBT2);
        W[(size_t)nn*128 + k] = f2bf(v);
    } else if (bb < 576) {
        int r = bb - 384; int layer = r >> 6; int i = ((r & 63) << 8) + t;
        float v;
        if (layer == 0) v = loadf(Wr0_h2f, (size_t)i, isbf);
        else            v = loadf(Wr_all, (size_t)((layer-1)*3)*16384 + i, isbf);
        ((layer == 0) ? w_h2f0 : ((layer == 1) ? w_h2f1 : w_h2f2))[i] = v;
    } else if (bb < 640) {
        // w_f2h0 padded to [128][128]: rows k>=97 zero
        int i = ((bb - 576) << 8) + t;
        int k = i >> 7;
        w_f2h0[i] = (k < FIN) ? loadf(Wr0_f2h, (size_t)i, isbf) : 0.f;
    } else if (bb < 704) {
        int i = ((bb - 640) << 8) + t;
        w_f2h1[i] = loadf(Wr_all, (size_t)1*16384 + i, isbf);
    } else if (bb < 768) {
        int i = ((bb - 704) << 8) + t;
        w_of2h0[i] = loadf(Wo0_f2h, (size_t)i, isbf);
    } else if (bb < 832) {
        int i = ((bb - 768) << 8) + t;
        w_of2h1[i] = loadf(Wo_all, (size_t)1*16384 + i, isbf);
    } else {
        if (t < 128) {
            b_comb0[t] = loadf(br0_h2f, t, isbf) + loadf(br0_rel, t, isbf);
            b_comb1[t] = loadf(br_all, 0*128 + t, isbf) + loadf(br_all, 2*128 + t, isbf);
            b_comb2[t] = loadf(br_all, 3*128 + t, isbf) + loadf(br_all, 5*128 + t, isbf);
            b_f2h0[t]  = loadf(br0_f2h, t, isbf);
            b_f2h1[t]  = loadf(br_all, 1*128 + t, isbf);
        }
    }
}

// ---------------- CSR build (3-region batched) ----------------
__global__ void k_zero3(int* c0, int* c1, int* c2){
    int bb = blockIdx.x, t = threadIdx.x;
    int* c; int n; int base;
    if (bb < NB_REL_N)              { c = c0; n = N_FLOWN; base = bb; }
    else if (bb < 2*NB_REL_N)       { c = c1; n = N_FLOWN; base = bb - NB_REL_N; }
    else                            { c = c2; n = N_HOSTN; base = bb - 2*NB_REL_N; }
    int i = base * 256 + t;
    if (i < n) c[i] = 0;
}
__global__ void k_hist3(const int* d0, const int* d1, const int* d2,
                        int* c0, int* c1, int* c2){
    int bb = blockIdx.x, t = threadIdx.x;
    const int* dst; int* cnt; int E; int base;
    if (bb < NB_REL_E)                   { dst = d0; cnt = c0; E = E_RELN; base = bb; }
    else if (bb < NB_REL_E + NB_HF_E)    { dst = d1; cnt = c1; E = E_HFN;  base = bb - NB_REL_E; }
    else                                 { dst = d2; cnt = c2; E = E_HFN;  base = bb - NB_REL_E - NB_HF_E; }
    int e = base * 256 + t;
    if (e < E) atomicAdd(&cnt[dst[e]], 1);
}
__global__ __launch_bounds__(256) void k_scan1_3(
    const int* c0, int* rp0, int* bs0,
    const int* c1, int* rp1, int* bs1,
    const int* c2, int* rp2, int* bs2)
{
    __shared__ int s[256];
    int bb = blockIdx.x, t = threadIdx.x;
    const int* cnt; int* rp; int* bsum; int n; int base;
    if (bb < NB_REL_N)            { cnt = c0; rp = rp0; bsum = bs0; n = N_FLOWN; base = bb; }
    else if (bb < 2*NB_REL_N)     { cnt = c1; rp = rp1; bsum = bs1; n = N_FLOWN; base = bb - NB_REL_N; }
    else                          { cnt = c2; rp = rp2; bsum = bs2; n = N_HOSTN; base = bb - 2*NB_REL_N; }
    int i = base * 256 + t;
    int v = (i < n) ? cnt[i] : 0;
    s[t] = v; __syncthreads();
    for (int off = 1; off < 256; off <<= 1) {
        int x = (t >= off) ? s[t - off] : 0;
        __syncthreads();
        s[t] += x;
        __syncthreads();
    }
    if (i < n) rp[i] = s[t] - v;
    if (t == 255) bsum[base] = s[255];
}
__global__ __launch_bounds__(256) void k_scan2_3(int* bs0, int* bs1, int* bs2){
    __shared__ int s[256];
    __shared__ int carry;
    int t = threadIdx.x;
    int* bsum; int nb;
    if (blockIdx.x == 0)      { bsum = bs0; nb = NB_REL_N; }
    else if (blockIdx.x == 1) { bsum = bs1; nb = NB_REL_N; }
    else                      { bsum = bs2; nb = NB_F2H_N; }
    if (t == 0) carry = 0;
    __syncthreads();
    for (int base = 0; base < nb; base += 256) {
        int i = base + t;
        int v = (i < nb) ? bsum[i] : 0;
        s[t] = v; __syncthreads();
        for (int off = 1; off < 256; off <<= 1) {
            int x = (t >= off) ? s[t - off] : 0;
            __syncthreads();
            s[t] += x;
            __syncthreads();
        }
        int excl = s[t] - v + carry;
        if (i < nb) bsum[i] = excl;
        __syncthreads();
        if (t == 255) carry += s[255];
        __syncthreads();
    }
}
__global__ void k_scan3_3(int* rp0, const int* bs0, int* w0,
                          int* rp1, const int* bs1, int* w1,
                          int* rp2, const int* bs2, int* w2)
{
    int bb = blockIdx.x, t = threadIdx.x;
    int* rp; const int* bsum; int* wr; int n, E, base;
    if (bb < NB_REL_N)        { rp = rp0; bsum = bs0; wr = w0; n = N_FLOWN; E = E_RELN; base = bb; }
    else if (bb < 2*NB_REL_N) { rp = rp1; bsum = bs1; wr = w1; n = N_FLOWN; E = E_HFN;  base = bb - NB_REL_N; }
    else                      { rp = rp2; bsum = bs2; wr = w2; n = N_HOSTN; E = E_HFN;  base = bb - 2*NB_REL_N; }
    int i = base * 256 + t;
    if (i < n) { int v = rp[i] + bsum[base]; rp[i] = v; wr[i] = v; }
    if (i == 0) rp[n] = E;
}
// class-partitioned placement: class = blockIdx%8 (round-robins onto XCDs);
// each ei/wr line belongs to one dst class -> single-XCD writes (heuristic).
__global__ __launch_bounds__(256) void k_place3c(
    const int* s0, const int* d0, int* w0, int* e0,
    const int* s1, const int* d1, int* w1, int* e1,
    const int* s2, const int* d2, int* w2, int* e2)
{
    const int bb = blockIdx.x;
    const int *src, *dst; int *wr, *ei; int E, divc, rb;
    if (bb < PLC_REL)      { src=s0; dst=d0; wr=w0; ei=e0; E=E_RELN; divc=25000; rb=bb; }
    else if (bb < PLC_H2F) { src=s1; dst=d1; wr=w1; ei=e1; E=E_HFN;  divc=25000; rb=bb-PLC_REL; }
    else                   { src=s2; dst=d2; wr=w2; ei=e2; E=E_HFN;  divc=2500;  rb=bb-PLC_H2F; }
    const int cls  = rb & 7;
    const int base = (rb >> 3) * 2048;
    const int t = threadIdx.x;
    #pragma unroll
    for (int i = 0; i < 8; ++i) {
        const int e = base + t + i * 256;
        if (e < E) {
            const int d = dst[e];
            if (d / divc == cls) {
                const int pos = atomicAdd(&wr[d], 1);
                ei[pos] = src[e];
            }
        }
    }
}

// ---------------- host-sized VALU GEMM: Y[M,128] (+)= X[M,K]@W[K,128]+b ---------
__global__ __launch_bounds__(256) void k_gemm128(
    const void* X, int xmode, const float* W, const float* bias,
    void* Y, int ybf, int M, int K, int accum, int dorelu, const int* flagp)
{
    const int isbf = (xmode == 2) ? *flagp : xmode;
    const int tid  = threadIdx.x;
    const int row0 = blockIdx.x * 16;
    __shared__ float sX[16][130];
    const int total = 16 * K;
    for (int i = tid; i < total; i += 256) {
        int r = i / K, c = i - r * K;
        int gr = row0 + r;
        sX[r][c] = (gr < M) ? loadf(X, (size_t)gr * K + c, isbf) : 0.f;
    }
    __syncthreads();

    const int c4 = (tid & 31) * 4;
    const int rb = tid >> 5;
    float a0x=0,a0y=0,a0z=0,a0w=0, a1x=0,a1y=0,a1z=0,a1w=0;
    #pragma unroll 4
    for (int k = 0; k < K; ++k) {
        const float4 w = *(const float4*)(W + (size_t)k * 128 + c4);
        const float x0 = sX[rb][k];
        const float x1 = sX[rb + 8][k];
        a0x = fmaf(x0, w.x, a0x); a0y = fmaf(x0, w.y, a0y);
        a0z = fmaf(x0, w.z, a0z); a0w = fmaf(x0, w.w, a0w);
        a1x = fmaf(x1, w.x, a1x); a1y = fmaf(x1, w.y, a1y);
        a1z = fmaf(x1, w.z, a1z); a1w = fmaf(x1, w.w, a1w);
    }
    float bx=0, by=0, bz=0, bw=0;
    if (bias) { const float4 b = *(const float4*)(bias + c4); bx=b.x; by=b.y; bz=b.z; bw=b.w; }

    #pragma unroll
    for (int h = 0; h < 2; ++h) {
        const int rr = row0 + rb + (h ? 8 : 0);
        if (rr >= M) continue;
        float v0 = (h?a1x:a0x)+bx, v1 = (h?a1y:a0y)+by;
        float v2 = (h?a1z:a0z)+bz, v3 = (h?a1w:a0w)+bw;
        if (ybf) {
            unsigned short* p = (unsigned short*)Y + (size_t)rr * 128 + c4;
            ushort4 o; o.x=f2bf(v0); o.y=f2bf(v1); o.z=f2bf(v2); o.w=f2bf(v3);
            *(ushort4*)p = o;
        } else {
            float* p = (float*)Y + (size_t)rr * 128 + c4;
            if (accum) { v0+=p[0]; v1+=p[1]; v2+=p[2]; v3+=p[3]; }
            if (dorelu) { v0=fmaxf(v0,0.f); v1=fmaxf(v1,0.f); v2=fmaxf(v2,0.f); v3=fmaxf(v3,0.f); }
            float4 o; o.x=v0; o.y=v1; o.z=v2; o.w=v3;
            *(float4*)p = o;
        }
    }
}

// ---------------- fused dual-input host GEMM: Y = relu(X1@W1 + X2@W2 + b) ------
__global__ __launch_bounds__(256) void k_gemm2in(
    const float* __restrict__ X1, const float* __restrict__ X2,
    const float* __restrict__ W1, const float* __restrict__ W2,
    const float* __restrict__ bias, float* __restrict__ Y, int M)
{
    const int tid  = threadIdx.x;
    const int row0 = blockIdx.x * 16;
    __shared__ float sX1[16][130];
    __shared__ float sX2[16][130];
    for (int i = tid; i < 16 * 128; i += 256) {
        int r = i >> 7, c = i & 127;
        int gr = row0 + r;
        sX1[r][c] = (gr < M) ? X1[(size_t)gr * 128 + c] : 0.f;
        sX2[r][c] = (gr < M) ? X2[(size_t)gr * 128 + c] : 0.f;
    }
    __syncthreads();

    const int c4 = (tid & 31) * 4;
    const int rb = tid >> 5;
    float a0x=0,a0y=0,a0z=0,a0w=0, a1x=0,a1y=0,a1z=0,a1w=0;
    #pragma unroll 4
    for (int k = 0; k < 128; ++k) {
        const float4 w = *(const float4*)(W1 + (size_t)k * 128 + c4);
        const float x0 = sX1[rb][k];
        const float x1 = sX1[rb + 8][k];
        a0x = fmaf(x0, w.x, a0x); a0y = fmaf(x0, w.y, a0y);
        a0z = fmaf(x0, w.z, a0z); a0w = fmaf(x0, w.w, a0w);
        a1x = fmaf(x1, w.x, a1x); a1y = fmaf(x1, w.y, a1y);
        a1z = fmaf(x1, w.z, a1z); a1w = fmaf(x1, w.w, a1w);
    }
    #pragma unroll 4
    for (int k = 0; k < 128; ++k) {
        const float4 w = *(const float4*)(W2 + (size_t)k * 128 + c4);
        const float x0 = sX2[rb][k];
        const float x1 = sX2[rb + 8][k];
        a0x = fmaf(x0, w.x, a0x); a0y = fmaf(x0, w.y, a0y);
        a0z = fmaf(x0, w.z, a0z); a0w = fmaf(x0, w.w, a0w);
        a1x = fmaf(x1, w.x, a1x); a1y = fmaf(x1, w.y, a1y);
        a1z = fmaf(x1, w.z, a1z); a1w = fmaf(x1, w.w, a1w);
    }
    const float4 b = *(const float4*)(bias + c4);
    #pragma unroll
    for (int h = 0; h < 2; ++h) {
        const int rr = row0 + rb + (h ? 8 : 0);
        if (rr >= M) continue;
        float4 o;
        o.x = fmaxf((h?a1x:a0x) + b.x, 0.f);
        o.y = fmaxf((h?a1y:a0y) + b.y, 0.f);
        o.z = fmaxf((h?a1z:a0z) + b.z, 0.f);
        o.w = fmaxf((h?a1w:a0w) + b.w, 0.f);
        *(float4*)(Y + (size_t)rr * 128 + c4) = o;
    }
}

// ---------------- MFMA dual flow GEMM: both outputs bf16, no bias ----------------
typedef __attribute__((ext_vector_type(8))) short bfrag;
typedef __attribute__((ext_vector_type(4))) float f32x4;

__global__ __launch_bounds__(256) void k_gemm_mfma(
    const unsigned short* __restrict__ Abf, const unsigned short* __restrict__ WBT,
    unsigned short* __restrict__ Y1, unsigned short* __restrict__ Y2, int M)
{
    const int tid  = threadIdx.x;
    const int wave = tid >> 6;
    const int lane = tid & 63;
    const int quad = lane >> 4;
    const int l16  = lane & 15;
    const int m0   = blockIdx.x * 32;

    __shared__ unsigned short sA[32 * 128];   // 8 KB, XOR-swizzled 16B units

    {
        const uint4* gsrc = (const uint4*)(Abf + (size_t)m0 * 128);
        uint4* sdst = (uint4*)sA;
        #pragma unroll
        for (int p = 0; p < 2; ++p) {
            int g = tid + p * 256;
            int row = g >> 4, u = g & 15;
            sdst[row * 16 + (u ^ (row & 15))] = gsrc[g];
        }
    }
    __syncthreads();

    f32x4 acc[2][4] = {};
    const int nbase = wave * 64;

    #pragma unroll
    for (int c = 0; c < 4; ++c) {
        const int un = (c * 4 + quad) ^ l16;
        bfrag a0 = *(const bfrag*)(sA + ((size_t)(l16)      * 128 + un * 8));
        bfrag a1 = *(const bfrag*)(sA + ((size_t)(16 + l16) * 128 + un * 8));
        #pragma unroll
        for (int j = 0; j < 4; ++j) {
            const bfrag b = *(const bfrag*)(WBT + (size_t)(nbase + j * 16 + l16) * 128
                                                 + c * 32 + quad * 8);
            acc[0][j] = __builtin_amdgcn_mfma_f32_16x16x32_bf16(a0, b, acc[0][j], 0, 0, 0);
            acc[1][j] = __builtin_amdgcn_mfma_f32_16x16x32_bf16(a1, b, acc[1][j], 0, 0, 0);
        }
    }

    unsigned short* Yd = (nbase < 128) ? Y1 : Y2;
    const int colb = nbase & 127;
    #pragma unroll
    for (int j = 0; j < 4; ++j) {
        const int col = colb + j * 16 + l16;
        #pragma unroll
        for (int i = 0; i < 2; ++i)
            #pragma unroll
            for (int r = 0; r < 4; ++r) {
                const int row = m0 + i * 16 + quad * 4 + r;
                Yd[(size_t)row * 128 + col] = f2bf(acc[i][j][r]);
            }
    }
}

// ---------------- CSR gather-aggregation (all-bf16, 4 dst/block, chunk-4 MLP) ----
// Xout[d] = relu?( root[d] + bias + sum_rel Zrel[s] + sum_h2f Zh2f[s] )
__global__ __launch_bounds__(256) void k_agg_flow(
    const unsigned short* __restrict__ Zrel, const unsigned short* __restrict__ Zh2f,
    const int* __restrict__ rp_rel, const int* __restrict__ ei_rel,
    const int* __restrict__ rp_h2f, const int* __restrict__ ei_h2f,
    const unsigned short* __restrict__ root, const float* __restrict__ bias,
    unsigned short* __restrict__ Xout, int do_relu)
{
    const int wave = threadIdx.x >> 6;
    const int lane = threadIdx.x & 63;
    const int d = blockIdx.x * 4 + wave;
    const int f2 = lane * 2;

    const ushort2 rv = *(const ushort2*)(root + (size_t)d * 128 + f2);
    const float2 bv = *(const float2*)(bias + f2);
    float a0 = bf2f(rv.x) + bv.x;
    float a1 = bf2f(rv.y) + bv.y;

    {   // rel edges: chunks of 4 -> 4 gathers in flight
        const int b0 = rp_rel[d], b1 = rp_rel[d + 1];
        int e = b0;
        for (; e + 4 <= b1; e += 4) {
            const int s0 = ei_rel[e];
            const int s1 = ei_rel[e + 1];
            const int s2 = ei_rel[e + 2];
            const int s3 = ei_rel[e + 3];
            const ushort2 z0 = *(const ushort2*)(Zrel + (size_t)s0 * 128 + f2);
            const ushort2 z1 = *(const ushort2*)(Zrel + (size_t)s1 * 128 + f2);
            const ushort2 z2 = *(const ushort2*)(Zrel + (size_t)s2 * 128 + f2);
            const ushort2 z3 = *(const ushort2*)(Zrel + (size_t)s3 * 128 + f2);
            a0 += (bf2f(z0.x) + bf2f(z1.x)) + (bf2f(z2.x) + bf2f(z3.x));
            a1 += (bf2f(z0.y) + bf2f(z1.y)) + (bf2f(z2.y) + bf2f(z3.y));
        }
        if (e + 2 <= b1) {
            const int s0 = ei_rel[e];
            const int s1 = ei_rel[e + 1];
            const ushort2 z0 = *(const ushort2*)(Zrel + (size_t)s0 * 128 + f2);
            const ushort2 z1 = *(const ushort2*)(Zrel + (size_t)s1 * 128 + f2);
            a0 += bf2f(z0.x) + bf2f(z1.x);
            a1 += bf2f(z0.y) + bf2f(z1.y);
            e += 2;
        }
        if (e < b1) {
            const int s = ei_rel[e];
            const ushort2 z = *(const ushort2*)(Zrel + (size_t)s * 128 + f2);
            a0 += bf2f(z.x); a1 += bf2f(z.y);
        }
    }
    {   // h2f edges: chunks of 4 + tail
        const int b0 = rp_h2f[d], b1 = rp_h2f[d + 1];
        int e = b0;
        for (; e + 4 <= b1; e += 4) {
            const int s0 = ei_h2f[e];
            const int s1 = ei_h2f[e + 1];
            const int s2 = ei_h2f[e + 2];
            const int s3 = ei_h2f[e + 3];
            const ushort2 z0 = *(const ushort2*)(Zh2f + (size_t)s0 * 128 + f2);
            const ushort2 z1 = *(const ushort2*)(Zh2f + (size_t)s1 * 128 + f2);
            const ushort2 z2 = *(const ushort2*)(Zh2f + (size_t)s2 * 128 + f2);
            const ushort2 z3 = *(const ushort2*)(Zh2f + (size_t)s3 * 128 + f2);
            a0 += (bf2f(z0.x) + bf2f(z1.x)) + (bf2f(z2.x) + bf2f(z3.x));
            a1 += (bf2f(z0.y) + bf2f(z1.y)) + (bf2f(z2.y) + bf2f(z3.y));
        }
        if (e + 2 <= b1) {
            const int s0 = ei_h2f[e];
            const int s1 = ei_h2f[e + 1];
            const ushort2 z0 = *(const ushort2*)(Zh2f + (size_t)s0 * 128 + f2);
            const ushort2 z1 = *(const ushort2*)(Zh2f + (size_t)s1 * 128 + f2);
            a0 += bf2f(z0.x) + bf2f(z1.x);
            a1 += bf2f(z0.y) + bf2f(z1.y);
            e += 2;
        }
        if (e < b1) {
            const int s = ei_h2f[e];
            const ushort2 z = *(const ushort2*)(Zh2f + (size_t)s * 128 + f2);
            a0 += bf2f(z.x); a1 += bf2f(z.y);
        }
    }
    if (do_relu) { a0 = fmaxf(a0, 0.f); a1 = fmaxf(a1, 0.f); }
    ushort2 o; o.x = f2bf(a0); o.y = f2bf(a1);
    *(ushort2*)(Xout + (size_t)d * 128 + f2) = o;
}

// host dst: out[d][0:128] = sum f2h Zbf[src][0:128]  (window-8 MLP)
__global__ __launch_bounds__(128) void k_agg_host(
    const unsigned short* __restrict__ Z, const int* __restrict__ rp,
    const int* __restrict__ ei, float* __restrict__ out)
{
    const int d = blockIdx.x, t = threadIdx.x;
    const int b0 = rp[d];
    const int n = rp[d + 1] - b0;
    float a = 0.f;
    for (int base = 0; base < n; base += 8) {
        const int cnt = min(8, n - base);
        unsigned short z[8];
        #pragma unroll
        for (int q = 0; q < 8; ++q)
            if (q < cnt) z[q] = Z[(size_t)ei[b0 + base + q] * 128 + t];
        #pragma unroll
        for (int q = 0; q < 8; ++q)
            if (q < cnt) a += bf2f(z[q]);
    }
    out[(size_t)d * 128 + t] = a;
}

// ---------------- pooling over sorted batch (bf16 input) ----------------
#define PCHUNK 128
__global__ __launch_bounds__(128) void k_pool2(const unsigned short* xf, const int* batch,
                                               unsigned* bits){
    const int t = threadIdx.x;
    const int i0 = blockIdx.x * PCHUNK;
    const int iend = min(i0 + PCHUNK, N_FLOWN);
    if (i0 >= N_FLOWN) return;
    float cur = -3.4e38f;
    int curg = batch[i0];
    for (int i = i0; i < iend; ++i) {
        int g = batch[i];
        if (g != curg) {
            unsigned u = __float_as_uint(cur);
            unsigned ord = (u & 0x80000000u) ? ~u : (u | 0x80000000u);
            atomicMax(&bits[(size_t)curg * 128 + t], ord);
            cur = -3.4e38f; curg = g;
        }
        cur = fmaxf(cur, bf2f(xf[(size_t)i * 128 + t]));
    }
    unsigned u = __float_as_uint(cur);
    unsigned ord = (u & 0x80000000u) ? ~u : (u | 0x80000000u);
    atomicMax(&bits[(size_t)curg * 128 + t], ord);
}

// ---------------- classifier ----------------
__global__ __launch_bounds__(128) void k_classifier(
    const unsigned* bits,
    const void* Wc1, const void* bc1, const void* Wc2, const void* bc2,
    const void* Wc3, const void* bc3, void* out, const int* flagp)
{
    const int g = blockIdx.x, t = threadIdx.x;
    const int isbf = *flagp;
    __shared__ float sp[128], sh1[64], sh2[128];
    {
        unsigned ord = bits[(size_t)g * HH + t];
        unsigned u = (ord & 0x80000000u) ? (ord & 0x7FFFFFFFu) : ~ord;
        sp[t] = __uint_as_float(u);
    }
    __syncthreads();
    if (t < 64) {
        float a = loadf(bc1, t, isbf);
        #pragma unroll 4
        for (int k = 0; k < 128; ++k) a = fmaf(sp[k], loadf(Wc1, k * 64 + t, isbf), a);
        sh1[t] = fmaxf(a, 0.f);
    }
    __syncthreads();
    {
        float a = loadf(bc2, t, isbf);
        #pragma unroll 4
        for (int k = 0; k < 64; ++k) a = fmaf(sh1[k], loadf(Wc2, k * 128 + t, isbf), a);
        sh2[t] = fmaxf(a, 0.f);
    }
    __syncthreads();
    if (t < NCN) {
        float a = loadf(bc3, t, isbf);
        #pragma unroll 4
        for (int k = 0; k < 128; ++k) a = fmaf(sh2[k], loadf(Wc3, k * NCN + t, isbf), a);
        if (isbf) ((unsigned short*)out)[(size_t)g * NCN + t] = f2bf(a);
        else      ((float*)out)[(size_t)g * NCN + t] = a;
    }
}

extern "C" void kernel_launch(void* const* d_in, const int* in_sizes, int n_in,
                              void* d_out, int out_size, void* d_ws, size_t ws_size,
                              hipStream_t stream)
{
    const int*  host_ids   = (const int*) d_in[0];
    const void* flow_x     = d_in[1];
    const int*  h2f_src    = (const int*) d_in[2];
    const int*  h2f_dst    = (const int*) d_in[3];
    const int*  f2h_src    = (const int*) d_in[4];
    const int*  f2h_dst    = (const int*) d_in[5];
    const int*  rel_src    = (const int*) d_in[6];
    const int*  rel_dst    = (const int*) d_in[7];
    const int*  flow_batch = (const int*) d_in[8];
    const void* host_embed = d_in[9];
    const void* Wr0_h2f = d_in[10]; const void* br0_h2f = d_in[11]; const void* Wo0_h2f = d_in[12];
    const void* Wr0_f2h = d_in[13]; const void* br0_f2h = d_in[14]; const void* Wo0_f2h = d_in[15];
    const void* Wr0_rel = d_in[16]; const void* br0_rel = d_in[17]; const void* Wo0_rel = d_in[18];
    const void* Wr_all  = d_in[19];
    const void* br_all  = d_in[20];
    const void* Wo_all  = d_in[21];
    const void* Wc1 = d_in[22]; const void* bc1 = d_in[23];
    const void* Wc2 = d_in[24]; const void* bc2 = d_in[25];
    const void* Wc3 = d_in[26]; const void* bc3 = d_in[27];

    // -------- workspace (~200 MB) --------
    size_t off = 0;
    auto alloc = [&](size_t bytes) -> char* {
        char* p = (char*)d_ws + off;
        off += (bytes + 255) & ~(size_t)255;
        return p;
    };
    unsigned short* F1bf  = (unsigned short*)alloc((size_t)N_FLOWN * HH * 2);  // state
    unsigned short* Froot = (unsigned short*)alloc((size_t)N_FLOWN * HH * 2);  // root term
    unsigned short* F2bf  = (unsigned short*)alloc((size_t)N_FLOWN * HH * 2);  // z_rel
    float* HA = (float*)alloc((size_t)N_HOSTN * HH * 4);
    float* HB = (float*)alloc((size_t)N_HOSTN * HH * 4);
    unsigned short* HCbf = (unsigned short*)alloc((size_t)N_HOSTN * HH * 2);   // z_h
    float* HD = (float*)alloc((size_t)N_HOSTN * HH * 4);
    unsigned short* WBT0 = (unsigned short*)alloc(256 * 128 * 2);
    unsigned short* WBT1 = (unsigned short*)alloc(256 * 128 * 2);
    unsigned short* WBT2 = (unsigned short*)alloc(256 * 128 * 2);
    float* w_h2f0  = (float*)alloc(128 * 128 * 4);
    float* w_h2f1  = (float*)alloc(128 * 128 * 4);
    float* w_h2f2  = (float*)alloc(128 * 128 * 4);
    float* w_f2h0  = (float*)alloc(128 * 128 * 4);
    float* w_f2h1  = (float*)alloc(128 * 128 * 4);
    float* w_of2h0 = (float*)alloc(128 * 128 * 4);
    float* w_of2h1 = (float*)alloc(128 * 128 * 4);
    float* b_comb0 = (float*)alloc(128 * 4);
    float* b_comb1 = (float*)alloc(128 * 4);
    float* b_comb2 = (float*)alloc(128 * 4);
    float* b_f2h0  = (float*)alloc(128 * 4);
    float* b_f2h1  = (float*)alloc(128 * 4);
    unsigned* poolbits = (unsigned*)alloc(GG * HH * 4);
    int* flagp = (int*)alloc(256);
    int* rp_rel = (int*)alloc((N_FLOWN + 1) * 4);
    int* ei_rel = (int*)alloc((size_t)E_RELN * 4);
    int* rp_h2f = (int*)alloc((N_FLOWN + 1) * 4);
    int* ei_h2f = (int*)alloc((size_t)E_HFN * 4);
    int* rp_f2h = (int*)alloc((N_HOSTN + 1) * 4);
    int* ei_f2h = (int*)alloc((size_t)E_HFN * 4);
    int* wr_rel = (int*)alloc((size_t)N_FLOWN * 4);
    int* wr_h2f = (int*)alloc((size_t)N_FLOWN * 4);
    int* wr_f2h = (int*)alloc((size_t)N_HOSTN * 4);
    int* bs0 = (int*)alloc(1024 * 4);
    int* bs1 = (int*)alloc(1024 * 4);
    int* bs2 = (int*)alloc(256 * 4);

    const int T = 256;
    #define GRID1(n) dim3(cdiv((long long)(n), T)), dim3(T), 0, stream

    if (off > ws_size) {
        k_flag_us<<<GRID1(out_size)>>>((unsigned short*)d_out, out_size, (unsigned short)0x4000);
        return;
    }

    k_detect<<<dim3(1), dim3(256), 0, stream>>>((const unsigned short*)flow_x, flagp);

    // -------- CSR builds (batched, 6 launches) --------
    k_zero3 <<<dim3(2*NB_REL_N + NB_F2H_N), dim3(256), 0, stream>>>(wr_rel, wr_h2f, wr_f2h);
    k_hist3 <<<dim3(NB_REL_E + 2*NB_HF_E), dim3(256), 0, stream>>>(rel_dst, h2f_dst, f2h_dst,
                                                                    wr_rel, wr_h2f, wr_f2h);
    k_scan1_3<<<dim3(2*NB_REL_N + NB_F2H_N), dim3(256), 0, stream>>>(
        wr_rel, rp_rel, bs0, wr_h2f, rp_h2f, bs1, wr_f2h, rp_f2h, bs2);
    k_scan2_3<<<dim3(3), dim3(256), 0, stream>>>(bs0, bs1, bs2);
    k_scan3_3<<<dim3(2*NB_REL_N + NB_F2H_N), dim3(256), 0, stream>>>(
        rp_rel, bs0, wr_rel, rp_h2f, bs1, wr_h2f, rp_f2h, bs2, wr_f2h);
    k_place3c<<<dim3(PLC_ALL), dim3(256), 0, stream>>>(
        rel_src, rel_dst, wr_rel, ei_rel,
        h2f_src, h2f_dst, wr_h2f, ei_h2f,
        f2h_src, f2h_dst, wr_f2h, ei_f2h);

    // -------- weight prep (1 launch) --------
    k_wprep_all<<<dim3(833), dim3(256), 0, stream>>>(
        Wr0_h2f, br0_h2f, Wo0_h2f, Wr0_f2h, br0_f2h, Wo0_f2h, Wr0_rel, br0_rel, Wo0_rel,
        Wr_all, br_all, Wo_all,
        WBT0, WBT1, WBT2, w_h2f0, w_h2f1, w_h2f2,
        w_f2h0, w_f2h1, w_of2h0, w_of2h1,
        b_comb0, b_comb1, b_comb2, b_f2h0, b_f2h1, flagp);

    // ================= layer 0 =================
    k_gather_embed<<<GRID1(N_HOSTN * HH)>>>(host_ids, host_embed, HA, flagp);
    k_pad_cast<<<GRID1((size_t)N_FLOWN * 128)>>>(flow_x, F1bf, flagp);
    // host path: gather bf16 input features (K padded to 128); fused dual GEMM + relu
    k_agg_host<<<dim3(N_HOSTN), dim3(128), 0, stream>>>(F1bf, rp_f2h, ei_f2h, HD);
    k_gemm2in<<<dim3(cdiv(N_HOSTN,16)), dim3(256), 0, stream>>>(HD, HA, w_f2h0, w_of2h0, b_f2h0, HB, N_HOSTN);
    // flow path
    k_gemm128<<<dim3(cdiv(N_HOSTN,16)), dim3(256), 0, stream>>>(HA, 0, w_h2f0, nullptr, HCbf, 1, N_HOSTN, 128, 0, 0, flagp);
    k_gemm_mfma<<<dim3(N_FLOWN/32), dim3(256), 0, stream>>>(F1bf, WBT0, Froot, F2bf, N_FLOWN);
    k_agg_flow<<<dim3(N_FLOWN/4), dim3(256), 0, stream>>>(F2bf, HCbf, rp_rel, ei_rel, rp_h2f, ei_h2f,
                                                          Froot, b_comb0, F1bf, 1);

    // ================= stacked layer 0 =================
    k_agg_host<<<dim3(N_HOSTN), dim3(128), 0, stream>>>(F1bf, rp_f2h, ei_f2h, HD);
    k_gemm128<<<dim3(cdiv(N_HOSTN,16)), dim3(256), 0, stream>>>(HB, 0, w_h2f1, nullptr, HCbf, 1, N_HOSTN, 128, 0, 0, flagp);
    k_gemm_mfma<<<dim3(N_FLOWN/32), dim3(256), 0, stream>>>(F1bf, WBT1, Froot, F2bf, N_FLOWN);
    k_agg_flow<<<dim3(N_FLOWN/4), dim3(256), 0, stream>>>(F2bf, HCbf, rp_rel, ei_rel, rp_h2f, ei_h2f,
                                                          Froot, b_comb1, F1bf, 1);
    k_gemm2in<<<dim3(cdiv(N_HOSTN,16)), dim3(256), 0, stream>>>(HD, HB, w_f2h1, w_of2h1, b_f2h1, HA, N_HOSTN);

    // ================= stacked layer 1 (last; no host update, no relu) =================
    k_gemm128<<<dim3(cdiv(N_HOSTN,16)), dim3(256), 0, stream>>>(HA, 0, w_h2f2, nullptr, HCbf, 1, N_HOSTN, 128, 0, 0, flagp);
    k_gemm_mfma<<<dim3(N_FLOWN/32), dim3(256), 0, stream>>>(F1bf, WBT2, Froot, F2bf, N_FLOWN);
    k_agg_flow<<<dim3(N_FLOWN/4), dim3(256), 0, stream>>>(F2bf, HCbf, rp_rel, ei_rel, rp_h2f, ei_h2f,
                                                          Froot, b_comb2, F1bf, 0);

    // ================= pool + classifier =================
    k_zero<<<GRID1(GG * HH)>>>((float*)poolbits, (size_t)GG * HH);
    k_pool2<<<dim3(cdiv(N_FLOWN, PCHUNK)), dim3(128), 0, stream>>>(F1bf, flow_batch, poolbits);
    k_classifier<<<dim3(GG), dim3(128), 0, stream>>>(poolbits, Wc1, bc1, Wc2, bc2, Wc3, bc3,
                                                     d_out, flagp);
    #undef GRID1
}